// Round 1
// baseline (252.407 us; speedup 1.0000x reference)
//
#include <hip/hip_runtime.h>
#include <cstdint>

#define B_SZ 2048
#define T_SZ 512
#define F_SZ 64
#define NG   12   // 4*H, H=3

// ---------- math helpers ----------
__device__ __forceinline__ float fast_rcp(float x) { return __builtin_amdgcn_rcpf(x); }
__device__ __forceinline__ float sigm(float x) { return fast_rcp(1.0f + __expf(-x)); }
__device__ __forceinline__ float tanh_fast(float x) {
    // tanh(x) = 2/(1+exp(-2x)) - 1 ; exact at saturation (exp->inf or ->0)
    return fmaf(2.0f, fast_rcp(1.0f + __expf(-2.0f * x)), -1.0f);
}

// Keras gate order: i, f, g, o in z[0:3], z[3:6], z[6:9], z[9:12]
__device__ __forceinline__ void cell_update(const float (&z)[12],
                                            float& h0, float& h1, float& h2,
                                            float& c0, float& c1, float& c2) {
    float cn0 = fmaf(sigm(z[3]), c0, sigm(z[0]) * tanh_fast(z[6]));
    float cn1 = fmaf(sigm(z[4]), c1, sigm(z[1]) * tanh_fast(z[7]));
    float cn2 = fmaf(sigm(z[5]), c2, sigm(z[2]) * tanh_fast(z[8]));
    c0 = cn0; c1 = cn1; c2 = cn2;
    h0 = sigm(z[9])  * tanh_fast(c0);
    h1 = sigm(z[10]) * tanh_fast(c1);
    h2 = sigm(z[11]) * tanh_fast(c2);
}

// ---------- phase 1: xw[t][b][g] = x[b][t][:] @ W + bias ----------
__global__ __launch_bounds__(256) void xw_phase(const float* __restrict__ x,
                                                const float* __restrict__ W,
                                                const float* __restrict__ bias,
                                                float* __restrict__ xw,
                                                int t0, int tc_len) {
    __shared__ float Ws[F_SZ * NG];
    __shared__ float bs[NG];
    const int tid = threadIdx.x;
    for (int i = tid; i < F_SZ * NG; i += 256) Ws[i] = W[i];
    if (tid < NG) bs[tid] = bias[tid];
    __syncthreads();

    const int r  = blockIdx.x * 256 + tid;   // r = tc*B + b  (write-coalesced)
    const int tc = r >> 11;                  // / 2048
    const int bb = r & (B_SZ - 1);
    if (tc >= tc_len) return;
    const int t = t0 + tc;

    const float* xp = x + ((size_t)bb * T_SZ + t) * F_SZ;
    float acc[NG];
    #pragma unroll
    for (int g = 0; g < NG; ++g) acc[g] = bs[g];

    #pragma unroll
    for (int f0 = 0; f0 < F_SZ; f0 += 4) {
        const float4 xv = *reinterpret_cast<const float4*>(xp + f0);
        #pragma unroll
        for (int j = 0; j < 4; ++j) {
            const float xs = (j == 0) ? xv.x : (j == 1) ? xv.y : (j == 2) ? xv.z : xv.w;
            const int f = f0 + j;
            const float4 w0 = *reinterpret_cast<const float4*>(&Ws[f * NG + 0]);
            const float4 w1 = *reinterpret_cast<const float4*>(&Ws[f * NG + 4]);
            const float4 w2 = *reinterpret_cast<const float4*>(&Ws[f * NG + 8]);
            acc[0] = fmaf(xs, w0.x, acc[0]);  acc[1] = fmaf(xs, w0.y, acc[1]);
            acc[2] = fmaf(xs, w0.z, acc[2]);  acc[3] = fmaf(xs, w0.w, acc[3]);
            acc[4] = fmaf(xs, w1.x, acc[4]);  acc[5] = fmaf(xs, w1.y, acc[5]);
            acc[6] = fmaf(xs, w1.z, acc[6]);  acc[7] = fmaf(xs, w1.w, acc[7]);
            acc[8] = fmaf(xs, w2.x, acc[8]);  acc[9] = fmaf(xs, w2.y, acc[9]);
            acc[10] = fmaf(xs, w2.z, acc[10]); acc[11] = fmaf(xs, w2.w, acc[11]);
        }
    }

    float* op = xw + (size_t)r * NG;   // 48B-aligned (48 % 16 == 0)
    *reinterpret_cast<float4*>(op + 0) = make_float4(acc[0], acc[1], acc[2], acc[3]);
    *reinterpret_cast<float4*>(op + 4) = make_float4(acc[4], acc[5], acc[6], acc[7]);
    *reinterpret_cast<float4*>(op + 8) = make_float4(acc[8], acc[9], acc[10], acc[11]);
}

// ---------- phase 2: sequential scan over a T-chunk ----------
__global__ __launch_bounds__(64) void lstm_scan(const float* __restrict__ xw,
                                                const float* __restrict__ U,
                                                const float* __restrict__ Wd,
                                                const float* __restrict__ bdp,
                                                float* __restrict__ out,
                                                float* __restrict__ hbuf,
                                                float* __restrict__ cbuf,
                                                int tc_len, int is_first, int is_last) {
    const int bb = blockIdx.x * 64 + threadIdx.x;

    float u[3][NG];
    #pragma unroll
    for (int j = 0; j < 3; ++j)
        #pragma unroll
        for (int g = 0; g < NG; ++g) u[j][g] = U[j * NG + g];  // uniform -> s_loads

    float h0, h1, h2, c0, c1, c2;
    if (is_first) {
        h0 = h1 = h2 = c0 = c1 = c2 = 0.0f;
    } else {
        h0 = hbuf[bb]; h1 = hbuf[bb + B_SZ]; h2 = hbuf[bb + 2 * B_SZ];
        c0 = cbuf[bb]; c1 = cbuf[bb + B_SZ]; c2 = cbuf[bb + 2 * B_SZ];
    }

    float4 pf[8][3];
    auto ldstep = [&](int t, float4 (&dst)[3]) {
        const float* p = xw + ((size_t)t * B_SZ + bb) * NG;
        dst[0] = *reinterpret_cast<const float4*>(p + 0);
        dst[1] = *reinterpret_cast<const float4*>(p + 4);
        dst[2] = *reinterpret_cast<const float4*>(p + 8);
    };
    auto comp = [&](const float4 (&zz)[3]) {
        float z[12] = { zz[0].x, zz[0].y, zz[0].z, zz[0].w,
                        zz[1].x, zz[1].y, zz[1].z, zz[1].w,
                        zz[2].x, zz[2].y, zz[2].z, zz[2].w };
        #pragma unroll
        for (int g = 0; g < NG; ++g)
            z[g] = fmaf(h2, u[2][g], fmaf(h1, u[1][g], fmaf(h0, u[0][g], z[g])));
        cell_update(z, h0, h1, h2, c0, c1, c2);
    };

    #pragma unroll
    for (int s = 0; s < 8; ++s) ldstep(s, pf[s]);      // requires tc_len >= 8

    for (int t = 0; t < tc_len; t += 8) {              // tc_len % 8 == 0
        #pragma unroll
        for (int s = 0; s < 8; ++s) {
            comp(pf[s]);
            if (t + 8 + s < tc_len) ldstep(t + 8 + s, pf[s]);
        }
    }

    if (is_last) {
        const float logit = bdp[0] + h0 * Wd[0] + h1 * Wd[1] + h2 * Wd[2];
        out[bb] = sigm(logit);
    } else {
        hbuf[bb] = h0; hbuf[bb + B_SZ] = h1; hbuf[bb + 2 * B_SZ] = h2;
        cbuf[bb] = c0; cbuf[bb + B_SZ] = c1; cbuf[bb + 2 * B_SZ] = c2;
    }
}

// ---------- fallback: fully fused, no workspace needed ----------
__global__ __launch_bounds__(64) void lstm_fused_fallback(const float* __restrict__ x,
                                                          const float* __restrict__ W,
                                                          const float* __restrict__ bias,
                                                          const float* __restrict__ U,
                                                          const float* __restrict__ Wd,
                                                          const float* __restrict__ bdp,
                                                          float* __restrict__ out) {
    __shared__ float Ws[F_SZ * NG];
    __shared__ float bs[NG];
    for (int i = threadIdx.x; i < F_SZ * NG; i += 64) Ws[i] = W[i];
    if (threadIdx.x < NG) bs[threadIdx.x] = bias[threadIdx.x];
    __syncthreads();

    const int bb = blockIdx.x * 64 + threadIdx.x;
    float u[3][NG];
    #pragma unroll
    for (int j = 0; j < 3; ++j)
        #pragma unroll
        for (int g = 0; g < NG; ++g) u[j][g] = U[j * NG + g];

    float h0 = 0, h1 = 0, h2 = 0, c0 = 0, c1 = 0, c2 = 0;
    const float* xp = x + (size_t)bb * T_SZ * F_SZ;

    for (int t = 0; t < T_SZ; ++t) {
        float z[12];
        #pragma unroll
        for (int g = 0; g < NG; ++g) z[g] = bs[g];
        #pragma unroll 4
        for (int f0 = 0; f0 < F_SZ; f0 += 4) {
            const float4 xv = *reinterpret_cast<const float4*>(xp + t * F_SZ + f0);
            #pragma unroll
            for (int j = 0; j < 4; ++j) {
                const float xs = (j == 0) ? xv.x : (j == 1) ? xv.y : (j == 2) ? xv.z : xv.w;
                const int f = f0 + j;
                #pragma unroll
                for (int g = 0; g < NG; ++g) z[g] = fmaf(xs, Ws[f * NG + g], z[g]);
            }
        }
        #pragma unroll
        for (int g = 0; g < NG; ++g)
            z[g] = fmaf(h2, u[2][g], fmaf(h1, u[1][g], fmaf(h0, u[0][g], z[g])));
        cell_update(z, h0, h1, h2, c0, c1, c2);
    }

    const float logit = bdp[0] + h0 * Wd[0] + h1 * Wd[1] + h2 * Wd[2];
    out[bb] = sigm(logit);
}

extern "C" void kernel_launch(void* const* d_in, const int* in_sizes, int n_in,
                              void* d_out, int out_size, void* d_ws, size_t ws_size,
                              hipStream_t stream) {
    (void)in_sizes; (void)n_in; (void)out_size;
    const float* x  = (const float*)d_in[0];
    const float* W  = (const float*)d_in[1];
    const float* U  = (const float*)d_in[2];
    const float* b  = (const float*)d_in[3];
    const float* Wd = (const float*)d_in[4];
    const float* bd = (const float*)d_in[5];
    float* out = (float*)d_out;

    const size_t state_bytes = (size_t)B_SZ * 6 * sizeof(float);
    const size_t avail = (ws_size > state_bytes) ? (ws_size - state_bytes) : 0;
    long long Tc = (long long)(avail / ((size_t)B_SZ * NG * sizeof(float)));
    if (Tc > T_SZ) Tc = T_SZ;
    Tc &= ~7LL;                       // multiple of 8 (scan pipeline depth)

    if (Tc < 8) {                     // workspace too small: fused slow path
        lstm_fused_fallback<<<B_SZ / 64, 64, 0, stream>>>(x, W, b, U, Wd, bd, out);
        return;
    }

    float* hbuf  = (float*)d_ws;
    float* cbuf  = hbuf + B_SZ * 3;
    float* xwbuf = cbuf + B_SZ * 3;

    for (int t0 = 0; t0 < T_SZ; t0 += (int)Tc) {
        const int len  = (T_SZ - t0 < (int)Tc) ? (T_SZ - t0) : (int)Tc;  // %8==0
        const int rows = len * B_SZ;
        xw_phase<<<rows / 256, 256, 0, stream>>>(x, W, b, xwbuf, t0, len);
        lstm_scan<<<B_SZ / 64, 64, 0, stream>>>(xwbuf, U, Wd, bd, out, hbuf, cbuf,
                                                len, t0 == 0 ? 1 : 0,
                                                (t0 + len >= T_SZ) ? 1 : 0);
    }
}

// Round 2
// 158.005 us; speedup vs baseline: 1.5975x; 1.5975x over previous
//
#include <hip/hip_runtime.h>
#include <cstdint>

#define B_SZ 2048
#define T_SZ 512
#define F_SZ 64
#define NG   12   // 4*H, H=3

// log2(e); gates are pre-scaled by -L2E (sigmoid) / -2*L2E (tanh) in phase 1
#define L2E 1.4426950408889634f

__device__ __forceinline__ float fast_rcp(float x) { return __builtin_amdgcn_rcpf(x); }
__device__ __forceinline__ float exp2h(float x)    { return __builtin_amdgcn_exp2f(x); }
// zs already scaled by -L2E:   sigmoid(z) = 1/(1+2^zs)
__device__ __forceinline__ float sigm_s(float zs)  { return fast_rcp(1.0f + exp2h(zs)); }
// zs already scaled by -2*L2E: tanh(z) = 2/(1+2^zs) - 1
__device__ __forceinline__ float tanh_s(float zs)  { return fmaf(2.0f, fast_rcp(1.0f + exp2h(zs)), -1.0f); }
// natural-argument versions (for final dense + fallback)
__device__ __forceinline__ float sigm_n(float x)   { return sigm_s(x * (-L2E)); }
__device__ __forceinline__ float tanh_n(float x)   { return tanh_s(x * (-2.0f * L2E)); }

template<int CTRL>
__device__ __forceinline__ float qperm(float v) {
    return __int_as_float(__builtin_amdgcn_mov_dpp(__float_as_int(v), CTRL, 0xF, 0xF, false));
}
// quad_perm selectors: lane k receives from src[k]
// A = [1,2,0,0] -> h_{(m+1)%3} ; B = [2,0,1,1] -> h_{(m+2)%3}   (m = {0,1,2,2})
#define QPA 9    // 1 | 2<<2 | 0<<4 | 0<<6
#define QPB 82   // 2 | 0<<2 | 1<<4 | 1<<6

// ---------------- phase 1: xw[t][b][m*4+q] = (x[b][t][:] @ W + bias) * scale(q) ----------------
// tile: 16 t x 16 b, 256 threads. Reads coalesced in t, writes coalesced via LDS transpose.
__global__ __launch_bounds__(256) void xw_phase(const float* __restrict__ x,
                                                const float* __restrict__ W,
                                                const float* __restrict__ bias,
                                                float* __restrict__ xw,
                                                int t0) {
    __shared__ float Ws[F_SZ * NG];      // reordered + scaled
    __shared__ float bs[NG];
    __shared__ float trs[16][196];       // [tt][bb*12 + p], padded row (196 % 4 == 0 -> 16B aligned rows)

    const int tid = threadIdx.x;
    for (int i = tid; i < F_SZ * NG; i += 256) {
        const int f = i / NG, p = i - f * NG;
        const int m = p >> 2, q = p & 3;
        const float sc = (q == 2) ? (-2.0f * L2E) : (-L2E);
        Ws[i] = W[f * NG + q * 3 + m] * sc;
    }
    if (tid < NG) {
        const int m = tid >> 2, q = tid & 3;
        const float sc = (q == 2) ? (-2.0f * L2E) : (-L2E);
        bs[tid] = bias[q * 3 + m] * sc;
    }
    __syncthreads();

    const int tileT = blockIdx.x;        // within chunk
    const int tileB = blockIdx.y;
    const int tt = tid & 15, bb = tid >> 4;
    const int t = t0 + tileT * 16 + tt;
    const int b = tileB * 16 + bb;

    const float* xp = x + ((size_t)b * T_SZ + t) * F_SZ;
    float acc[NG];
    #pragma unroll
    for (int p = 0; p < NG; ++p) acc[p] = bs[p];

    #pragma unroll
    for (int f0 = 0; f0 < F_SZ; f0 += 4) {
        const float4 xv = *reinterpret_cast<const float4*>(xp + f0);
        #pragma unroll
        for (int j = 0; j < 4; ++j) {
            const float xs = (j == 0) ? xv.x : (j == 1) ? xv.y : (j == 2) ? xv.z : xv.w;
            const float* wr = &Ws[(f0 + j) * NG];
            #pragma unroll
            for (int p = 0; p < NG; ++p) acc[p] = fmaf(xs, wr[p], acc[p]);
        }
    }

    // LDS transpose
    float* ld = &trs[tt][bb * NG];
    *reinterpret_cast<float4*>(ld + 0) = make_float4(acc[0], acc[1], acc[2],  acc[3]);
    *reinterpret_cast<float4*>(ld + 4) = make_float4(acc[4], acc[5], acc[6],  acc[7]);
    *reinterpret_cast<float4*>(ld + 8) = make_float4(acc[8], acc[9], acc[10], acc[11]);
    __syncthreads();

    // write out: 16 rows (t) x 192 floats contiguous each
    const int r = tid >> 4, off = (tid & 15) * NG;
    const float* lp = &trs[r][off];
    float* op = xw + ((size_t)(tileT * 16 + r) * B_SZ + tileB * 16) * NG + off;
    *reinterpret_cast<float4*>(op + 0) = *reinterpret_cast<const float4*>(lp + 0);
    *reinterpret_cast<float4*>(op + 4) = *reinterpret_cast<const float4*>(lp + 4);
    *reinterpret_cast<float4*>(op + 8) = *reinterpret_cast<const float4*>(lp + 8);
}

// ---------------- phase 2: quad-per-element scan ----------------
// 4 lanes per batch element; lane k owns hidden unit m = min(k,2) (lane 3 duplicates m=2).
// h exchange via DPP quad_perm. 8192 threads total.
__global__ __launch_bounds__(64) void lstm_scan(const float* __restrict__ xw,
                                                const float* __restrict__ U,
                                                const float* __restrict__ Wd,
                                                const float* __restrict__ bdp,
                                                float* __restrict__ out,
                                                float* __restrict__ hbuf,
                                                float* __restrict__ cbuf,
                                                int len, int is_first, int is_last) {
    const int g = blockIdx.x * 64 + threadIdx.x;
    const int elem = g >> 2;
    const int k = g & 3;
    const int m  = (k < 3) ? k : 2;
    const int mn = (m + 1 == 3) ? 0 : m + 1;
    const int mp = (m + 2 >= 3) ? m - 1 : m + 2;

    // per-lane scaled U coefficients for this lane's 4 gates (q=0:i,1:f,2:g,3:o; col = q*3+m)
    float u_own[4], u_nxt[4], u_prv[4];
    #pragma unroll
    for (int q = 0; q < 4; ++q) {
        const float sc = (q == 2) ? (-2.0f * L2E) : (-L2E);
        const int col = q * 3 + m;
        u_own[q] = U[m  * NG + col] * sc;
        u_nxt[q] = U[mn * NG + col] * sc;
        u_prv[q] = U[mp * NG + col] * sc;
    }

    float h, c, hA, hB;
    if (is_first) {
        h = c = hA = hB = 0.0f;
    } else {
        h = hbuf[g]; c = cbuf[g];
        hA = qperm<QPA>(h); hB = qperm<QPB>(h);
    }

    const size_t stride = (size_t)B_SZ * NG;              // floats per t-step
    const float* base = xw + (size_t)elem * NG + m * 4;

    float4 pf[8];
    #pragma unroll
    for (int s = 0; s < 8; ++s)
        pf[s] = *reinterpret_cast<const float4*>(base + (size_t)s * stride);
    const float* pnext = base + 8 * stride;

    for (int t = 0; t < len; t += 8) {
        #pragma unroll
        for (int s = 0; s < 8; ++s) {
            const float4 z4 = pf[s];
            if (t + 8 + s < len) pf[s] = *reinterpret_cast<const float4*>(pnext);
            pnext += stride;
            const float z0 = fmaf(hB, u_prv[0], fmaf(hA, u_nxt[0], fmaf(h, u_own[0], z4.x)));
            const float z1 = fmaf(hB, u_prv[1], fmaf(hA, u_nxt[1], fmaf(h, u_own[1], z4.y)));
            const float z2 = fmaf(hB, u_prv[2], fmaf(hA, u_nxt[2], fmaf(h, u_own[2], z4.z)));
            const float z3 = fmaf(hB, u_prv[3], fmaf(hA, u_nxt[3], fmaf(h, u_own[3], z4.w)));
            const float ai = sigm_s(z0);
            const float af = sigm_s(z1);
            const float ag = tanh_s(z2);
            const float ao = sigm_s(z3);
            c = fmaf(af, c, ai * ag);
            h = ao * tanh_n(c);
            hA = qperm<QPA>(h);
            hB = qperm<QPB>(h);
        }
    }

    if (is_last) {
        const float logit = bdp[0] + h * Wd[m] + hA * Wd[mn] + hB * Wd[mp];
        if (k == 0) out[elem] = sigm_n(logit);
    } else {
        hbuf[g] = h; cbuf[g] = c;
    }
}

// ---------------- fallback: fully fused, no workspace needed ----------------
__global__ __launch_bounds__(64) void lstm_fused_fallback(const float* __restrict__ x,
                                                          const float* __restrict__ W,
                                                          const float* __restrict__ bias,
                                                          const float* __restrict__ U,
                                                          const float* __restrict__ Wd,
                                                          const float* __restrict__ bdp,
                                                          float* __restrict__ out) {
    __shared__ float Ws[F_SZ * NG];
    __shared__ float bs[NG];
    for (int i = threadIdx.x; i < F_SZ * NG; i += 64) Ws[i] = W[i];
    if (threadIdx.x < NG) bs[threadIdx.x] = bias[threadIdx.x];
    __syncthreads();

    const int bb = blockIdx.x * 64 + threadIdx.x;
    float u[3][NG];
    #pragma unroll
    for (int j = 0; j < 3; ++j)
        #pragma unroll
        for (int gq = 0; gq < NG; ++gq) u[j][gq] = U[j * NG + gq];

    float h0 = 0, h1 = 0, h2 = 0, c0 = 0, c1 = 0, c2 = 0;
    const float* xp = x + (size_t)bb * T_SZ * F_SZ;

    for (int t = 0; t < T_SZ; ++t) {
        float z[NG];
        #pragma unroll
        for (int gq = 0; gq < NG; ++gq) z[gq] = bs[gq];
        #pragma unroll 4
        for (int f0 = 0; f0 < F_SZ; f0 += 4) {
            const float4 xv = *reinterpret_cast<const float4*>(xp + t * F_SZ + f0);
            #pragma unroll
            for (int j = 0; j < 4; ++j) {
                const float xs = (j == 0) ? xv.x : (j == 1) ? xv.y : (j == 2) ? xv.z : xv.w;
                #pragma unroll
                for (int gq = 0; gq < NG; ++gq) z[gq] = fmaf(xs, Ws[(f0 + j) * NG + gq], z[gq]);
            }
        }
        #pragma unroll
        for (int gq = 0; gq < NG; ++gq)
            z[gq] = fmaf(h2, u[2][gq], fmaf(h1, u[1][gq], fmaf(h0, u[0][gq], z[gq])));
        const float i0 = sigm_n(z[0]), i1 = sigm_n(z[1]), i2 = sigm_n(z[2]);
        const float f0g = sigm_n(z[3]), f1 = sigm_n(z[4]), f2 = sigm_n(z[5]);
        const float g0 = tanh_n(z[6]), g1 = tanh_n(z[7]), g2 = tanh_n(z[8]);
        const float o0 = sigm_n(z[9]), o1 = sigm_n(z[10]), o2 = sigm_n(z[11]);
        c0 = fmaf(f0g, c0, i0 * g0); c1 = fmaf(f1, c1, i1 * g1); c2 = fmaf(f2, c2, i2 * g2);
        h0 = o0 * tanh_n(c0); h1 = o1 * tanh_n(c1); h2 = o2 * tanh_n(c2);
    }

    const float logit = bdp[0] + h0 * Wd[0] + h1 * Wd[1] + h2 * Wd[2];
    out[bb] = sigm_n(logit);
}

extern "C" void kernel_launch(void* const* d_in, const int* in_sizes, int n_in,
                              void* d_out, int out_size, void* d_ws, size_t ws_size,
                              hipStream_t stream) {
    (void)in_sizes; (void)n_in; (void)out_size;
    const float* x  = (const float*)d_in[0];
    const float* W  = (const float*)d_in[1];
    const float* U  = (const float*)d_in[2];
    const float* b  = (const float*)d_in[3];
    const float* Wd = (const float*)d_in[4];
    const float* bd = (const float*)d_in[5];
    float* out = (float*)d_out;

    const size_t state_bytes = (size_t)B_SZ * 4 * 2 * sizeof(float);   // h,c per lane-group
    const size_t avail = (ws_size > state_bytes) ? (ws_size - state_bytes) : 0;
    long long Tc = (long long)(avail / ((size_t)B_SZ * NG * sizeof(float)));
    if (Tc > T_SZ) Tc = T_SZ;
    Tc &= ~15LL;                     // tiles of 16 t; also satisfies scan's %8

    if (Tc < 16) {                   // workspace too small: fused slow path
        lstm_fused_fallback<<<B_SZ / 64, 64, 0, stream>>>(x, W, b, U, Wd, bd, out);
        return;
    }

    float* hbuf  = (float*)d_ws;
    float* cbuf  = hbuf + (size_t)B_SZ * 4;
    float* xwbuf = cbuf + (size_t)B_SZ * 4;

    for (int t0 = 0; t0 < T_SZ; t0 += (int)Tc) {
        const int len = (T_SZ - t0 < (int)Tc) ? (T_SZ - t0) : (int)Tc;   // multiple of 16
        dim3 grid(len / 16, B_SZ / 16);
        xw_phase<<<grid, 256, 0, stream>>>(x, W, b, xwbuf, t0);
        lstm_scan<<<(B_SZ * 4) / 64, 64, 0, stream>>>(xwbuf, U, Wd, bd, out, hbuf, cbuf,
                                                      len, t0 == 0 ? 1 : 0,
                                                      (t0 + len >= T_SZ) ? 1 : 0);
    }
}